// Round 8
// baseline (372.464 us; speedup 1.0000x reference)
//
#include <hip/hip_runtime.h>
#include <hip/hip_cooperative_groups.h>
#include <cmath>

namespace cg = cooperative_groups;

namespace {
constexpr int B_ = 2, K_ = 4, D_ = 128, L_ = 4096, N_ = 16, R_ = 8, C_ = 40;
constexpr int CHUNK = 32, NCH = L_ / CHUNK;   // 128 chunks of 32
constexpr float LOG2E = 1.44269504f;
}

#if __has_builtin(__builtin_amdgcn_exp2f)
#define FEXP2(x) __builtin_amdgcn_exp2f(x)
#else
#define FEXP2(x) exp2f(x)
#endif

// ===========================================================================
// FUSED cooperative kernel. Grid 256 blocks x 512 thr. Block (bk, lt):
// l-tile = 128 l's = 4 chunks. Phase A: projections (k1 job-loop) -> global
// dts/BT/CT (block-private, L1/L2-hot). syncthreads. Stage into LDS.
// Phase B: pass-1 scan, u+delta HELD IN REGISTERS. grid sync.
// Chain: tid<64 = k25 port. grid sync. Phase C: pass-2 using persisted regs.
// ===========================================================================
__global__ __launch_bounds__(512, 2) void fused(
    const float* __restrict__ qx, const float* __restrict__ kv,
    const float* __restrict__ xw, const float* __restrict__ dtw,
    const float* __restrict__ dtb, const float* __restrict__ alg,
    const float* __restrict__ DsG,
    float* __restrict__ dtsT, float* __restrict__ BT, float* __restrict__ CT,
    float* __restrict__ hend, float* __restrict__ hinit,
    float* __restrict__ Ssum, float* __restrict__ out)
{
    __shared__ float Wt[D_ * C_];        // 20.5 KB  [d][c]
    __shared__ float dts_s[128 * R_];    //  4 KB    [l][r]
    __shared__ float B_s[128 * N_];      //  8 KB    [l][n]
    __shared__ float C_s[128 * N_];      //  8 KB    [l][n]
    __shared__ float y_s[D_ * 133];      // 68 KB    [d][l], stride 133 (5d%32 bijective)

    const int tid = threadIdx.x;
    const int w = tid >> 6, lane = tid & 63;
    const int bk = blockIdx.x >> 5;      // 0..7
    const int k  = bk & 3;
    const int lt = blockIdx.x & 31;      // l-tile of 128

    // ---- Phase B identity (also used to issue u-loads early) ----
    const int chl = tid >> 7;            // chunk-local 0..3
    const int d   = tid & 127;
    const int ch  = lt * 4 + chl;

    // issue u loads NOW: independent of phase A; latency hides under phase A
    float uu[CHUNK];
    {
        const float4* up = (const float4*)(kv + ((size_t)bk * D_ + d) * L_ + ch * CHUNK);
        #pragma unroll
        for (int j = 0; j < 8; ++j) {
            const float4 v = up[j];
            uu[4*j] = v.x; uu[4*j+1] = v.y; uu[4*j+2] = v.z; uu[4*j+3] = v.w;
        }
    }

    // ---- Phase A: projections (k1 port; 8 waves run 10 jobs) ----
    for (int i = tid; i < C_ * D_; i += 512) {
        const int c = i >> 7, dd = i & 127;
        Wt[dd * C_ + c] = xw[(k * C_ + c) * D_ + dd];
    }
    __syncthreads();
    {
        const int dg = lane >> 5, lq = lane & 31;
        for (int job = w; job < 10; job += 8) {
            const float* xsrc = (job >= 6) ? qx : kv;
            const int c0 = job * 4;
            float acc[4][4];
            #pragma unroll
            for (int c = 0; c < 4; ++c)
                #pragma unroll
                for (int j = 0; j < 4; ++j) acc[c][j] = 0.f;

            const float* src = xsrc + ((size_t)bk * D_ + dg * 64) * L_ + lt * 128 + 4 * lq;
            #pragma unroll 8
            for (int dd = 0; dd < 64; ++dd) {
                const float4 x = *(const float4*)(src + (size_t)dd * L_);
                const float4 wv = *(const float4*)&Wt[(dg * 64 + dd) * C_ + c0];
                const float* wp = (const float*)&wv;
                #pragma unroll
                for (int c = 0; c < 4; ++c) {
                    acc[c][0] = fmaf(x.x, wp[c], acc[c][0]);
                    acc[c][1] = fmaf(x.y, wp[c], acc[c][1]);
                    acc[c][2] = fmaf(x.z, wp[c], acc[c][2]);
                    acc[c][3] = fmaf(x.w, wp[c], acc[c][3]);
                }
            }
            #pragma unroll
            for (int c = 0; c < 4; ++c)
                #pragma unroll
                for (int j = 0; j < 4; ++j)
                    acc[c][j] += __shfl_xor(acc[c][j], 32, 64);

            if (dg == 0) {
                #pragma unroll
                for (int j = 0; j < 4; ++j) {
                    const int l = lt * 128 + 4 * lq + j;
                    float4 o; o.x = acc[0][j]; o.y = acc[1][j]; o.z = acc[2][j]; o.w = acc[3][j];
                    if (job < 2)
                        *(float4*)(dtsT + ((size_t)bk * L_ + l) * R_ + job * 4) = o;
                    else if (job < 6)
                        *(float4*)(BT + ((size_t)bk * L_ + l) * N_ + (job - 2) * 4) = o;
                    else
                        *(float4*)(CT + ((size_t)bk * L_ + l) * N_ + (job - 6) * 4) = o;
                }
            }
        }
    }
    __syncthreads();   // drains vmcnt: dts/BT/CT visible block-wide (same CU)

    // ---- Stage this l-tile's dts/B/C into LDS (L1-hot reads) ----
    {
        const float4* s1 = (const float4*)(dtsT + ((size_t)bk * L_ + lt * 128) * R_);
        if (tid < 256) ((float4*)dts_s)[tid] = s1[tid];
        const float4* s2 = (const float4*)(BT + ((size_t)bk * L_ + lt * 128) * N_);
        ((float4*)B_s)[tid] = s2[tid];
        const float4* s3 = (const float4*)(CT + ((size_t)bk * L_ + lt * 128) * N_);
        ((float4*)C_s)[tid] = s3[tid];
    }

    // per-thread scan constants
    float dtwr[R_];
    {
        const float* p = dtw + ((size_t)k * D_ + d) * R_;
        *(float4*)&dtwr[0] = *(const float4*)p;
        *(float4*)&dtwr[4] = *(const float4*)(p + 4);
    }
    const float bias = dtb[k * D_ + d];
    float A2[N_];
    {
        const float* ap = alg + ((size_t)k * D_ + d) * N_;
        #pragma unroll
        for (int j = 0; j < 4; ++j) {
            float4 a = *(const float4*)(ap + 4 * j);
            A2[4*j]   = -__expf(a.x) * LOG2E; A2[4*j+1] = -__expf(a.y) * LOG2E;
            A2[4*j+2] = -__expf(a.z) * LOG2E; A2[4*j+3] = -__expf(a.w) * LOG2E;
        }
    }
    __syncthreads();

    // ---- Phase B: pass-1 scan; delta kept in regs ----
    float dlt[CHUNK];
    {
        float h[N_];
        #pragma unroll
        for (int n = 0; n < N_; ++n) h[n] = 0.f;
        float sd = 0.f;

        #pragma unroll
        for (int l = 0; l < CHUNK; ++l) {
            float dv[R_];
            *(float4*)&dv[0] = *(const float4*)&dts_s[(chl * 32 + l) * R_];
            *(float4*)&dv[4] = *(const float4*)&dts_s[(chl * 32 + l) * R_ + 4];
            float s = bias;
            #pragma unroll
            for (int r = 0; r < R_; ++r) s = fmaf(dv[r], dtwr[r], s);
            const float e = FEXP2(s * LOG2E);
            const float dl = (s > 15.f) ? s : __logf(1.f + e);
            dlt[l] = dl;
            sd += dl;
            const float xb = dl * uu[l];
            #pragma unroll
            for (int g = 0; g < 4; ++g) {
                const float4 bg = *(const float4*)&B_s[(chl * 32 + l) * N_ + 4 * g];
                h[4*g+0] = fmaf(FEXP2(dl * A2[4*g+0]), h[4*g+0], xb * bg.x);
                h[4*g+1] = fmaf(FEXP2(dl * A2[4*g+1]), h[4*g+1], xb * bg.y);
                h[4*g+2] = fmaf(FEXP2(dl * A2[4*g+2]), h[4*g+2], xb * bg.z);
                h[4*g+3] = fmaf(FEXP2(dl * A2[4*g+3]), h[4*g+3], xb * bg.w);
            }
        }
        float* hp = hend + (((size_t)bk * NCH + ch) * D_ + d) * N_;
        #pragma unroll
        for (int j = 0; j < 4; ++j) {
            float4 o; o.x = h[4*j]; o.y = h[4*j+1]; o.z = h[4*j+2]; o.w = h[4*j+3];
            *(float4*)(hp + 4 * j) = o;
        }
        Ssum[((size_t)bk * NCH + ch) * D_ + d] = sd;
    }

    __threadfence();
    cg::this_grid().sync();

    // ---- Chain: exclusive prefix over chunks (k25 port, tid<64) ----
    if (tid < 64) {
        const int tg = blockIdx.x * 64 + tid;      // 16384 total
        const int n2 = tg & 15;
        const int d2 = (tg >> 4) & 127;
        const int bk2 = tg >> 11;
        const int k2 = bk2 & 3;
        const float A2c = -__expf(alg[((size_t)k2 * D_ + d2) * N_ + n2]) * LOG2E;
        float hh = 0.f;
        for (int c0 = 0; c0 < NCH; c0 += 16) {
            float he[16], ss[16];
            #pragma unroll
            for (int j = 0; j < 16; ++j) {
                const size_t si = ((size_t)bk2 * NCH + c0 + j) * D_ + d2;
                he[j] = hend[si * N_ + n2];
                ss[j] = Ssum[si];
            }
            #pragma unroll
            for (int j = 0; j < 16; ++j) {
                const size_t si = ((size_t)bk2 * NCH + c0 + j) * D_ + d2;
                hinit[si * N_ + n2] = hh;
                hh = fmaf(FEXP2(ss[j] * A2c), hh, he[j]);
            }
        }
    }

    __threadfence();
    cg::this_grid().sync();

    // ---- Phase C: pass-2 scan using persisted uu/dlt/A2 ----
    {
        float h[N_];
        const float* hp = hinit + (((size_t)bk * NCH + ch) * D_ + d) * N_;
        #pragma unroll
        for (int j = 0; j < 4; ++j) {
            float4 v = *(const float4*)(hp + 4 * j);
            h[4*j] = v.x; h[4*j+1] = v.y; h[4*j+2] = v.z; h[4*j+3] = v.w;
        }
        const float Dv = DsG[k * D_ + d];

        #pragma unroll
        for (int l = 0; l < CHUNK; ++l) {
            const float dl = dlt[l];
            const float xb = dl * uu[l];
            float p0 = 0.f, p1 = 0.f;
            #pragma unroll
            for (int g = 0; g < 4; ++g) {
                const float4 bg = *(const float4*)&B_s[(chl * 32 + l) * N_ + 4 * g];
                const float4 cg4 = *(const float4*)&C_s[(chl * 32 + l) * N_ + 4 * g];
                h[4*g+0] = fmaf(FEXP2(dl * A2[4*g+0]), h[4*g+0], xb * bg.x);
                p0 = fmaf(h[4*g+0], cg4.x, p0);
                h[4*g+1] = fmaf(FEXP2(dl * A2[4*g+1]), h[4*g+1], xb * bg.y);
                p1 = fmaf(h[4*g+1], cg4.y, p1);
                h[4*g+2] = fmaf(FEXP2(dl * A2[4*g+2]), h[4*g+2], xb * bg.z);
                p0 = fmaf(h[4*g+2], cg4.z, p0);
                h[4*g+3] = fmaf(FEXP2(dl * A2[4*g+3]), h[4*g+3], xb * bg.w);
                p1 = fmaf(h[4*g+3], cg4.w, p1);
            }
            y_s[d * 133 + chl * 32 + l] = fmaf(uu[l], Dv, p0 + p1);
        }
    }
    __syncthreads();

    // flush: 128 d-rows x 128 l, coalesced float4 stores (scalar LDS reads)
    #pragma unroll
    for (int p = 0; p < 8; ++p) {
        const int f = tid + p * 512;          // 0..4095
        const int row = f >> 5, c4 = (f & 31) * 4;
        const float* yp = &y_s[row * 133 + c4];
        float4 o; o.x = yp[0]; o.y = yp[1]; o.z = yp[2]; o.w = yp[3];
        *(float4*)(out + ((size_t)bk * D_ + row) * L_ + lt * 128 + c4) = o;
    }
}

// ===========================================================================
// Fallback path: round-7 kernels (used only if cooperative launch fails).
// ===========================================================================
__global__ __launch_bounds__(640, 2) void k1_proj(
    const float* __restrict__ qx, const float* __restrict__ kv,
    const float* __restrict__ xw,
    float* __restrict__ dtsT, float* __restrict__ BT, float* __restrict__ CT)
{
    __shared__ float Wt[D_ * C_];
    const int tid = threadIdx.x;
    const int w = tid >> 6, lane = tid & 63;
    const int dg = lane >> 5, lq = lane & 31;
    int blk = blockIdx.x;
    const int lt = blk & 31; blk >>= 5;
    const int k = blk & 3; const int b = blk >> 2;
    const int bk = b * K_ + k;

    for (int i = tid; i < C_ * D_; i += 640) {
        const int c = i >> 7, d = i & 127;
        Wt[d * C_ + c] = xw[(k * C_ + c) * D_ + d];
    }
    __syncthreads();

    const float* xsrc = (w >= 6) ? qx : kv;
    const int c0 = w * 4;
    float acc[4][4];
    #pragma unroll
    for (int c = 0; c < 4; ++c)
        #pragma unroll
        for (int j = 0; j < 4; ++j) acc[c][j] = 0.f;

    const float* src = xsrc + ((size_t)bk * D_ + dg * 64) * L_ + lt * 128 + 4 * lq;
    #pragma unroll 8
    for (int dd = 0; dd < 64; ++dd) {
        const float4 x = *(const float4*)(src + (size_t)dd * L_);
        const float4 wv = *(const float4*)&Wt[(dg * 64 + dd) * C_ + c0];
        const float* wp = (const float*)&wv;
        #pragma unroll
        for (int c = 0; c < 4; ++c) {
            acc[c][0] = fmaf(x.x, wp[c], acc[c][0]);
            acc[c][1] = fmaf(x.y, wp[c], acc[c][1]);
            acc[c][2] = fmaf(x.z, wp[c], acc[c][2]);
            acc[c][3] = fmaf(x.w, wp[c], acc[c][3]);
        }
    }
    #pragma unroll
    for (int c = 0; c < 4; ++c)
        #pragma unroll
        for (int j = 0; j < 4; ++j)
            acc[c][j] += __shfl_xor(acc[c][j], 32, 64);

    if (dg == 0) {
        #pragma unroll
        for (int j = 0; j < 4; ++j) {
            const int l = lt * 128 + 4 * lq + j;
            float4 o; o.x = acc[0][j]; o.y = acc[1][j]; o.z = acc[2][j]; o.w = acc[3][j];
            if (w < 2)
                *(float4*)(dtsT + ((size_t)bk * L_ + l) * R_ + w * 4) = o;
            else if (w < 6)
                *(float4*)(BT + ((size_t)bk * L_ + l) * N_ + (w - 2) * 4) = o;
            else
                *(float4*)(CT + ((size_t)bk * L_ + l) * N_ + (w - 6) * 4) = o;
        }
    }
}

__global__ __launch_bounds__(128, 1) void k2_pass1(
    const float* __restrict__ kv, const float* __restrict__ dtsT,
    const float* __restrict__ BT, const float* __restrict__ alg,
    const float* __restrict__ dtw, const float* __restrict__ dtb,
    float* __restrict__ hend, float* __restrict__ Ssum)
{
    __shared__ float dts_s[CHUNK * R_];
    __shared__ float B_s[CHUNK * N_];
    const int tid = threadIdx.x;
    const int d = tid;
    const int blk = blockIdx.x;
    const int ch = blk & (NCH - 1);
    const int bk = blk >> 7;
    const int k = bk & 3;

    {
        const float* src = dtsT + ((size_t)bk * L_ + ch * CHUNK) * R_;
        if (tid < 64) *(float4*)&dts_s[4 * tid] = *(const float4*)(src + 4 * tid);
        const float* bsrc = BT + ((size_t)bk * L_ + ch * CHUNK) * N_;
        *(float4*)&B_s[4 * tid] = *(const float4*)(bsrc + 4 * tid);
    }
    float uu[CHUNK];
    {
        const float4* up = (const float4*)(kv + ((size_t)bk * D_ + d) * L_ + ch * CHUNK);
        #pragma unroll
        for (int j = 0; j < 8; ++j) {
            const float4 v = up[j];
            uu[4*j] = v.x; uu[4*j+1] = v.y; uu[4*j+2] = v.z; uu[4*j+3] = v.w;
        }
    }
    float dtwr[R_];
    {
        const float* p = dtw + ((size_t)k * D_ + d) * R_;
        *(float4*)&dtwr[0] = *(const float4*)p;
        *(float4*)&dtwr[4] = *(const float4*)(p + 4);
    }
    const float bias = dtb[k * D_ + d];
    float A2[N_];
    {
        const float* ap = alg + ((size_t)k * D_ + d) * N_;
        #pragma unroll
        for (int j = 0; j < 4; ++j) {
            float4 a = *(const float4*)(ap + 4 * j);
            A2[4*j]   = -__expf(a.x) * LOG2E; A2[4*j+1] = -__expf(a.y) * LOG2E;
            A2[4*j+2] = -__expf(a.z) * LOG2E; A2[4*j+3] = -__expf(a.w) * LOG2E;
        }
    }
    __syncthreads();

    float h[N_];
    #pragma unroll
    for (int n = 0; n < N_; ++n) h[n] = 0.f;
    float sd = 0.f;
    #pragma unroll
    for (int l = 0; l < CHUNK; ++l) {
        float dv[R_];
        *(float4*)&dv[0] = *(const float4*)&dts_s[l * R_];
        *(float4*)&dv[4] = *(const float4*)&dts_s[l * R_ + 4];
        float s = bias;
        #pragma unroll
        for (int r = 0; r < R_; ++r) s = fmaf(dv[r], dtwr[r], s);
        const float e = FEXP2(s * LOG2E);
        const float dlt = (s > 15.f) ? s : __logf(1.f + e);
        sd += dlt;
        const float xb = dlt * uu[l];
        #pragma unroll
        for (int g = 0; g < 4; ++g) {
            const float4 bg = *(const float4*)&B_s[l * N_ + 4 * g];
            h[4*g+0] = fmaf(FEXP2(dlt * A2[4*g+0]), h[4*g+0], xb * bg.x);
            h[4*g+1] = fmaf(FEXP2(dlt * A2[4*g+1]), h[4*g+1], xb * bg.y);
            h[4*g+2] = fmaf(FEXP2(dlt * A2[4*g+2]), h[4*g+2], xb * bg.z);
            h[4*g+3] = fmaf(FEXP2(dlt * A2[4*g+3]), h[4*g+3], xb * bg.w);
        }
    }
    float* hp = hend + (((size_t)bk * NCH + ch) * D_ + d) * N_;
    #pragma unroll
    for (int j = 0; j < 4; ++j) {
        float4 o; o.x = h[4*j]; o.y = h[4*j+1]; o.z = h[4*j+2]; o.w = h[4*j+3];
        *(float4*)(hp + 4 * j) = o;
    }
    Ssum[((size_t)bk * NCH + ch) * D_ + d] = sd;
}

__global__ __launch_bounds__(64, 2) void k25_chain(
    const float* __restrict__ alg, const float* __restrict__ Ssum,
    const float* __restrict__ hend, float* __restrict__ hinit)
{
    const int tg = blockIdx.x * 64 + threadIdx.x;
    const int n = tg & 15;
    const int d = (tg >> 4) & 127;
    const int bk = tg >> 11;
    const int k = bk & 3;
    const float A2 = -__expf(alg[((size_t)k * D_ + d) * N_ + n]) * LOG2E;
    float h = 0.f;
    for (int c0 = 0; c0 < NCH; c0 += 32) {
        float he[32], ss[32];
        #pragma unroll
        for (int j = 0; j < 32; ++j) {
            const size_t si = ((size_t)bk * NCH + c0 + j) * D_ + d;
            he[j] = hend[si * N_ + n];
            ss[j] = Ssum[si];
        }
        #pragma unroll
        for (int j = 0; j < 32; ++j) {
            const size_t si = ((size_t)bk * NCH + c0 + j) * D_ + d;
            hinit[si * N_ + n] = h;
            h = fmaf(FEXP2(ss[j] * A2), h, he[j]);
        }
    }
}

__global__ __launch_bounds__(128, 1) void k3_pass2(
    const float* __restrict__ kv, const float* __restrict__ dtsT,
    const float* __restrict__ BT, const float* __restrict__ CT,
    const float* __restrict__ alg, const float* __restrict__ dtw,
    const float* __restrict__ dtb, const float* __restrict__ DsG,
    const float* __restrict__ hinit, float* __restrict__ out)
{
    constexpr int YS = CHUNK + 1;
    __shared__ float dts_s[CHUNK * R_];
    __shared__ float B_s[CHUNK * N_];
    __shared__ float C_s[CHUNK * N_];
    __shared__ float y_s[D_ * YS];
    const int tid = threadIdx.x;
    const int d = tid;
    const int blk = blockIdx.x;
    const int ch = blk & (NCH - 1);
    const int bk = blk >> 7;
    const int k = bk & 3;

    {
        const float* src = dtsT + ((size_t)bk * L_ + ch * CHUNK) * R_;
        if (tid < 64) *(float4*)&dts_s[4 * tid] = *(const float4*)(src + 4 * tid);
        const float* bsrc = BT + ((size_t)bk * L_ + ch * CHUNK) * N_;
        *(float4*)&B_s[4 * tid] = *(const float4*)(bsrc + 4 * tid);
        const float* csrc = CT + ((size_t)bk * L_ + ch * CHUNK) * N_;
        *(float4*)&C_s[4 * tid] = *(const float4*)(csrc + 4 * tid);
    }
    float uu[CHUNK];
    {
        const float4* up = (const float4*)(kv + ((size_t)bk * D_ + d) * L_ + ch * CHUNK);
        #pragma unroll
        for (int j = 0; j < 8; ++j) {
            const float4 v = up[j];
            uu[4*j] = v.x; uu[4*j+1] = v.y; uu[4*j+2] = v.z; uu[4*j+3] = v.w;
        }
    }
    float dtwr[R_];
    {
        const float* p = dtw + ((size_t)k * D_ + d) * R_;
        *(float4*)&dtwr[0] = *(const float4*)p;
        *(float4*)&dtwr[4] = *(const float4*)(p + 4);
    }
    const float bias = dtb[k * D_ + d];
    const float Dv = DsG[k * D_ + d];
    float A2[N_];
    {
        const float* ap = alg + ((size_t)k * D_ + d) * N_;
        #pragma unroll
        for (int j = 0; j < 4; ++j) {
            float4 a = *(const float4*)(ap + 4 * j);
            A2[4*j]   = -__expf(a.x) * LOG2E; A2[4*j+1] = -__expf(a.y) * LOG2E;
            A2[4*j+2] = -__expf(a.z) * LOG2E; A2[4*j+3] = -__expf(a.w) * LOG2E;
        }
    }
    float h[N_];
    {
        const float* hp = hinit + (((size_t)bk * NCH + ch) * D_ + d) * N_;
        #pragma unroll
        for (int j = 0; j < 4; ++j) {
            float4 v = *(const float4*)(hp + 4 * j);
            h[4*j] = v.x; h[4*j+1] = v.y; h[4*j+2] = v.z; h[4*j+3] = v.w;
        }
    }
    __syncthreads();

    #pragma unroll
    for (int l = 0; l < CHUNK; ++l) {
        float dv[R_];
        *(float4*)&dv[0] = *(const float4*)&dts_s[l * R_];
        *(float4*)&dv[4] = *(const float4*)&dts_s[l * R_ + 4];
        float s = bias;
        #pragma unroll
        for (int r = 0; r < R_; ++r) s = fmaf(dv[r], dtwr[r], s);
        const float e = FEXP2(s * LOG2E);
        const float dlt = (s > 15.f) ? s : __logf(1.f + e);
        const float xb = dlt * uu[l];
        float p0 = 0.f, p1 = 0.f;
        #pragma unroll
        for (int g = 0; g < 4; ++g) {
            const float4 bg = *(const float4*)&B_s[l * N_ + 4 * g];
            const float4 cg4 = *(const float4*)&C_s[l * N_ + 4 * g];
            h[4*g+0] = fmaf(FEXP2(dlt * A2[4*g+0]), h[4*g+0], xb * bg.x);
            p0 = fmaf(h[4*g+0], cg4.x, p0);
            h[4*g+1] = fmaf(FEXP2(dlt * A2[4*g+1]), h[4*g+1], xb * bg.y);
            p1 = fmaf(h[4*g+1], cg4.y, p1);
            h[4*g+2] = fmaf(FEXP2(dlt * A2[4*g+2]), h[4*g+2], xb * bg.z);
            p0 = fmaf(h[4*g+2], cg4.z, p0);
            h[4*g+3] = fmaf(FEXP2(dlt * A2[4*g+3]), h[4*g+3], xb * bg.w);
            p1 = fmaf(h[4*g+3], cg4.w, p1);
        }
        y_s[d * YS + l] = fmaf(uu[l], Dv, p0 + p1);
    }
    __syncthreads();

    #pragma unroll
    for (int p = 0; p < 8; ++p) {
        const int f = tid + p * 128;
        const int row = f >> 3, j4 = (f & 7) * 4;
        const float* yp = &y_s[row * YS + j4];
        float4 o; o.x = yp[0]; o.y = yp[1]; o.z = yp[2]; o.w = yp[3];
        *(float4*)(out + ((size_t)bk * D_ + row) * L_ + ch * CHUNK + j4) = o;
    }
}

extern "C" void kernel_launch(void* const* d_in, const int* in_sizes, int n_in,
                              void* d_out, int out_size, void* d_ws, size_t ws_size,
                              hipStream_t stream)
{
    const float* qx  = (const float*)d_in[0];
    const float* kv  = (const float*)d_in[1];
    const float* xw  = (const float*)d_in[2];
    const float* dtw = (const float*)d_in[3];
    const float* dtb = (const float*)d_in[4];
    const float* alg = (const float*)d_in[5];
    const float* Ds  = (const float*)d_in[6];
    float* out = (float*)d_out;

    const size_t sz_dts = (size_t)B_ * K_ * L_ * R_;        //   262,144
    const size_t sz_bc  = (size_t)B_ * K_ * L_ * N_;        //   524,288
    const size_t sz_h   = (size_t)B_ * K_ * NCH * D_ * N_;  // 2,097,152
    const size_t sz_ss  = (size_t)B_ * K_ * NCH * D_;       //   131,072
    const size_t need = (sz_dts + 2 * sz_bc + 2 * sz_h + sz_ss) * sizeof(float);
    if (ws_size < need) return;   // ~22.5 MB

    float* dts   = (float*)d_ws;
    float* BTp   = dts + sz_dts;
    float* CTp   = BTp + sz_bc;
    float* hend  = CTp + sz_bc;
    float* hinit = hend + sz_h;
    float* Ssm   = hinit + sz_h;

    void* args[] = { (void*)&qx, (void*)&kv, (void*)&xw, (void*)&dtw,
                     (void*)&dtb, (void*)&alg, (void*)&Ds,
                     (void*)&dts, (void*)&BTp, (void*)&CTp,
                     (void*)&hend, (void*)&hinit, (void*)&Ssm, (void*)&out };
    hipError_t err = hipLaunchCooperativeKernel(
        (void*)fused, dim3(B_ * K_ * 32), dim3(512), args, 0, stream);

    if (err != hipSuccess) {
        // fallback: round-7 four-kernel path (identical numerics)
        k1_proj<<<B_ * K_ * 32, 640, 0, stream>>>(qx, kv, xw, dts, BTp, CTp);
        k2_pass1<<<B_ * K_ * NCH, 128, 0, stream>>>(kv, dts, BTp, alg, dtw, dtb, hend, Ssm);
        k25_chain<<<256, 64, 0, stream>>>(alg, Ssm, hend, hinit);
        k3_pass2<<<B_ * K_ * NCH, 128, 0, stream>>>(kv, dts, BTp, CTp, alg, dtw, dtb, Ds, hinit, out);
    }
}

// Round 9
// 219.783 us; speedup vs baseline: 1.6947x; 1.6947x over previous
//
#include <hip/hip_runtime.h>
#include <hip/hip_cooperative_groups.h>
#include <cmath>

namespace cg = cooperative_groups;

namespace {
constexpr int B_ = 2, K_ = 4, D_ = 128, L_ = 4096, N_ = 16, R_ = 8, C_ = 40;
constexpr int CHUNK = 32, NCH = L_ / CHUNK;   // 128 chunks of 32
constexpr float LOG2E = 1.44269504f;
}

#if __has_builtin(__builtin_amdgcn_exp2f)
#define FEXP2(x) __builtin_amdgcn_exp2f(x)
#else
#define FEXP2(x) exp2f(x)
#endif

// ===========================================================================
// FUSED cooperative kernel, v2 (spill-proofed). Grid 256 x 512 thr.
// Block (bk, lt): l-tile = 128 l's = 4 chunks x 128 d.
// Phase A: projections -> DIRECT to LDS (no global relay).
// Phase B: pass-1 scan (u in regs), write hend/Ssum. grid sync.
// Chain: tid<64 exclusive prefix over chunks. grid sync.
// Phase C: recompute delta from LDS, pass-2 scan, direct reg->global stores.
// Persisted regs across syncs: uu[32], A2[16], dtwr[8], bias, Dv (~60).
// ===========================================================================
__global__ __launch_bounds__(512) void fused(
    const float* __restrict__ qx, const float* __restrict__ kv,
    const float* __restrict__ xw, const float* __restrict__ dtw,
    const float* __restrict__ dtb, const float* __restrict__ alg,
    const float* __restrict__ DsG,
    float* __restrict__ hend, float* __restrict__ hinit,
    float* __restrict__ Ssum, float* __restrict__ out)
{
    __shared__ float Wt[D_ * C_];        // 20.5 KB [d][c]
    __shared__ float dts_s[128 * R_];    //  4 KB   [l][r]
    __shared__ float B_s[128 * N_];      //  8 KB   [l][n]
    __shared__ float C_s[128 * N_];      //  8 KB   [l][n]

    const int tid = threadIdx.x;
    const int w = tid >> 6, lane = tid & 63;
    const int bk = blockIdx.x >> 5;      // 0..7
    const int k  = bk & 3;
    const int lt = blockIdx.x & 31;      // l-tile of 128

    const int chl = tid >> 7;            // chunk-local 0..3
    const int d   = tid & 127;
    const int ch  = lt * 4 + chl;

    // issue u loads early; latency hides under phase A
    float uu[CHUNK];
    {
        const float4* up = (const float4*)(kv + ((size_t)bk * D_ + d) * L_ + ch * CHUNK);
        #pragma unroll
        for (int j = 0; j < 8; ++j) {
            const float4 v = up[j];
            uu[4*j] = v.x; uu[4*j+1] = v.y; uu[4*j+2] = v.z; uu[4*j+3] = v.w;
        }
    }

    // ---- Phase A: projections, direct to LDS ----
    for (int i = tid; i < C_ * D_; i += 512) {
        const int c = i >> 7, dd = i & 127;
        Wt[dd * C_ + c] = xw[(k * C_ + c) * D_ + dd];
    }
    __syncthreads();
    {
        const int dg = lane >> 5, lq = lane & 31;
        for (int job = w; job < 10; job += 8) {
            const float* xsrc = (job >= 6) ? qx : kv;
            const int c0 = job * 4;
            float acc[4][4];
            #pragma unroll
            for (int c = 0; c < 4; ++c)
                #pragma unroll
                for (int j = 0; j < 4; ++j) acc[c][j] = 0.f;

            const float* src = xsrc + ((size_t)bk * D_ + dg * 64) * L_ + lt * 128 + 4 * lq;
            #pragma unroll 8
            for (int dd = 0; dd < 64; ++dd) {
                const float4 x = *(const float4*)(src + (size_t)dd * L_);
                const float4 wv = *(const float4*)&Wt[(dg * 64 + dd) * C_ + c0];
                const float* wp = (const float*)&wv;
                #pragma unroll
                for (int c = 0; c < 4; ++c) {
                    acc[c][0] = fmaf(x.x, wp[c], acc[c][0]);
                    acc[c][1] = fmaf(x.y, wp[c], acc[c][1]);
                    acc[c][2] = fmaf(x.z, wp[c], acc[c][2]);
                    acc[c][3] = fmaf(x.w, wp[c], acc[c][3]);
                }
            }
            #pragma unroll
            for (int c = 0; c < 4; ++c)
                #pragma unroll
                for (int j = 0; j < 4; ++j)
                    acc[c][j] += __shfl_xor(acc[c][j], 32, 64);

            // both d-half groups write 2 l-slots each (halves conflict width)
            #pragma unroll
            for (int jj = 0; jj < 2; ++jj) {
                const int j2 = dg * 2 + jj;
                const int ll = 4 * lq + j2;           // l_local 0..127
                float4 o; o.x = acc[0][j2]; o.y = acc[1][j2]; o.z = acc[2][j2]; o.w = acc[3][j2];
                if (job < 2)      *(float4*)&dts_s[ll * R_ + job * 4] = o;
                else if (job < 6) *(float4*)&B_s[ll * N_ + (job - 2) * 4] = o;
                else              *(float4*)&C_s[ll * N_ + (job - 6) * 4] = o;
            }
        }
    }

    // per-thread scan constants
    float dtwr[R_];
    {
        const float* p = dtw + ((size_t)k * D_ + d) * R_;
        *(float4*)&dtwr[0] = *(const float4*)p;
        *(float4*)&dtwr[4] = *(const float4*)(p + 4);
    }
    const float bias = dtb[k * D_ + d];
    const float Dv = DsG[k * D_ + d];
    float A2[N_];
    {
        const float* ap = alg + ((size_t)k * D_ + d) * N_;
        #pragma unroll
        for (int j = 0; j < 4; ++j) {
            float4 a = *(const float4*)(ap + 4 * j);
            A2[4*j]   = -__expf(a.x) * LOG2E; A2[4*j+1] = -__expf(a.y) * LOG2E;
            A2[4*j+2] = -__expf(a.z) * LOG2E; A2[4*j+3] = -__expf(a.w) * LOG2E;
        }
    }
    __syncthreads();

    // ---- Phase B: pass-1 scan ----
    {
        float h[N_];
        #pragma unroll
        for (int n = 0; n < N_; ++n) h[n] = 0.f;
        float sd = 0.f;

        #pragma unroll
        for (int l = 0; l < CHUNK; ++l) {
            const int ll = chl * 32 + l;
            float dv[R_];
            *(float4*)&dv[0] = *(const float4*)&dts_s[ll * R_];
            *(float4*)&dv[4] = *(const float4*)&dts_s[ll * R_ + 4];
            float s = bias;
            #pragma unroll
            for (int r = 0; r < R_; ++r) s = fmaf(dv[r], dtwr[r], s);
            const float e = FEXP2(s * LOG2E);
            const float dl = (s > 15.f) ? s : __logf(1.f + e);
            sd += dl;
            const float xb = dl * uu[l];
            #pragma unroll
            for (int g = 0; g < 4; ++g) {
                const float4 bg = *(const float4*)&B_s[ll * N_ + 4 * g];
                h[4*g+0] = fmaf(FEXP2(dl * A2[4*g+0]), h[4*g+0], xb * bg.x);
                h[4*g+1] = fmaf(FEXP2(dl * A2[4*g+1]), h[4*g+1], xb * bg.y);
                h[4*g+2] = fmaf(FEXP2(dl * A2[4*g+2]), h[4*g+2], xb * bg.z);
                h[4*g+3] = fmaf(FEXP2(dl * A2[4*g+3]), h[4*g+3], xb * bg.w);
            }
        }
        float* hp = hend + (((size_t)bk * NCH + ch) * D_ + d) * N_;
        #pragma unroll
        for (int j = 0; j < 4; ++j) {
            float4 o; o.x = h[4*j]; o.y = h[4*j+1]; o.z = h[4*j+2]; o.w = h[4*j+3];
            *(float4*)(hp + 4 * j) = o;
        }
        Ssum[((size_t)bk * NCH + ch) * D_ + d] = sd;
    }

    __threadfence();
    cg::this_grid().sync();

    // ---- Chain: exclusive prefix over chunks (tid<64) ----
    if (tid < 64) {
        const int tg = blockIdx.x * 64 + tid;      // 16384 total
        const int n2 = tg & 15;
        const int d2 = (tg >> 4) & 127;
        const int bk2 = tg >> 11;
        const int k2 = bk2 & 3;
        const float A2c = -__expf(alg[((size_t)k2 * D_ + d2) * N_ + n2]) * LOG2E;
        float hh = 0.f;
        for (int c0 = 0; c0 < NCH; c0 += 16) {
            float he[16], ss[16];
            #pragma unroll
            for (int j = 0; j < 16; ++j) {
                const size_t si = ((size_t)bk2 * NCH + c0 + j) * D_ + d2;
                he[j] = hend[si * N_ + n2];
                ss[j] = Ssum[si];
            }
            #pragma unroll
            for (int j = 0; j < 16; ++j) {
                const size_t si = ((size_t)bk2 * NCH + c0 + j) * D_ + d2;
                hinit[si * N_ + n2] = hh;
                hh = fmaf(FEXP2(ss[j] * A2c), hh, he[j]);
            }
        }
    }

    __threadfence();
    cg::this_grid().sync();

    // ---- Phase C: pass-2 scan, delta recomputed, direct stores ----
    {
        float h[N_];
        const float* hp = hinit + (((size_t)bk * NCH + ch) * D_ + d) * N_;
        #pragma unroll
        for (int j = 0; j < 4; ++j) {
            float4 v = *(const float4*)(hp + 4 * j);
            h[4*j] = v.x; h[4*j+1] = v.y; h[4*j+2] = v.z; h[4*j+3] = v.w;
        }
        float* orow = out + ((size_t)bk * D_ + d) * L_ + ch * CHUNK;
        float4 yv;

        #pragma unroll
        for (int l = 0; l < CHUNK; ++l) {
            const int ll = chl * 32 + l;
            float dv[R_];
            *(float4*)&dv[0] = *(const float4*)&dts_s[ll * R_];
            *(float4*)&dv[4] = *(const float4*)&dts_s[ll * R_ + 4];
            float s = bias;
            #pragma unroll
            for (int r = 0; r < R_; ++r) s = fmaf(dv[r], dtwr[r], s);
            const float e = FEXP2(s * LOG2E);
            const float dl = (s > 15.f) ? s : __logf(1.f + e);
            const float xb = dl * uu[l];
            float p0 = 0.f, p1 = 0.f;
            #pragma unroll
            for (int g = 0; g < 4; ++g) {
                const float4 bg  = *(const float4*)&B_s[ll * N_ + 4 * g];
                const float4 cg4 = *(const float4*)&C_s[ll * N_ + 4 * g];
                h[4*g+0] = fmaf(FEXP2(dl * A2[4*g+0]), h[4*g+0], xb * bg.x);
                p0 = fmaf(h[4*g+0], cg4.x, p0);
                h[4*g+1] = fmaf(FEXP2(dl * A2[4*g+1]), h[4*g+1], xb * bg.y);
                p1 = fmaf(h[4*g+1], cg4.y, p1);
                h[4*g+2] = fmaf(FEXP2(dl * A2[4*g+2]), h[4*g+2], xb * bg.z);
                p0 = fmaf(h[4*g+2], cg4.z, p0);
                h[4*g+3] = fmaf(FEXP2(dl * A2[4*g+3]), h[4*g+3], xb * bg.w);
                p1 = fmaf(h[4*g+3], cg4.w, p1);
            }
            ((float*)&yv)[l & 3] = fmaf(uu[l], Dv, p0 + p1);
            if ((l & 3) == 3) *(float4*)(orow + (l - 3)) = yv;
        }
    }
}

// ===========================================================================
// Fallback: round-7 four-kernel path (used only if cooperative launch fails).
// ===========================================================================
__global__ __launch_bounds__(640, 2) void k1_proj(
    const float* __restrict__ qx, const float* __restrict__ kv,
    const float* __restrict__ xw,
    float* __restrict__ dtsT, float* __restrict__ BT, float* __restrict__ CT)
{
    __shared__ float Wt[D_ * C_];
    const int tid = threadIdx.x;
    const int w = tid >> 6, lane = tid & 63;
    const int dg = lane >> 5, lq = lane & 31;
    int blk = blockIdx.x;
    const int lt = blk & 31; blk >>= 5;
    const int k = blk & 3; const int b = blk >> 2;
    const int bk = b * K_ + k;

    for (int i = tid; i < C_ * D_; i += 640) {
        const int c = i >> 7, d = i & 127;
        Wt[d * C_ + c] = xw[(k * C_ + c) * D_ + d];
    }
    __syncthreads();

    const float* xsrc = (w >= 6) ? qx : kv;
    const int c0 = w * 4;
    float acc[4][4];
    #pragma unroll
    for (int c = 0; c < 4; ++c)
        #pragma unroll
        for (int j = 0; j < 4; ++j) acc[c][j] = 0.f;

    const float* src = xsrc + ((size_t)bk * D_ + dg * 64) * L_ + lt * 128 + 4 * lq;
    #pragma unroll 8
    for (int dd = 0; dd < 64; ++dd) {
        const float4 x = *(const float4*)(src + (size_t)dd * L_);
        const float4 wv = *(const float4*)&Wt[(dg * 64 + dd) * C_ + c0];
        const float* wp = (const float*)&wv;
        #pragma unroll
        for (int c = 0; c < 4; ++c) {
            acc[c][0] = fmaf(x.x, wp[c], acc[c][0]);
            acc[c][1] = fmaf(x.y, wp[c], acc[c][1]);
            acc[c][2] = fmaf(x.z, wp[c], acc[c][2]);
            acc[c][3] = fmaf(x.w, wp[c], acc[c][3]);
        }
    }
    #pragma unroll
    for (int c = 0; c < 4; ++c)
        #pragma unroll
        for (int j = 0; j < 4; ++j)
            acc[c][j] += __shfl_xor(acc[c][j], 32, 64);

    if (dg == 0) {
        #pragma unroll
        for (int j = 0; j < 4; ++j) {
            const int l = lt * 128 + 4 * lq + j;
            float4 o; o.x = acc[0][j]; o.y = acc[1][j]; o.z = acc[2][j]; o.w = acc[3][j];
            if (w < 2)
                *(float4*)(dtsT + ((size_t)bk * L_ + l) * R_ + w * 4) = o;
            else if (w < 6)
                *(float4*)(BT + ((size_t)bk * L_ + l) * N_ + (w - 2) * 4) = o;
            else
                *(float4*)(CT + ((size_t)bk * L_ + l) * N_ + (w - 6) * 4) = o;
        }
    }
}

__global__ __launch_bounds__(128, 1) void k2_pass1(
    const float* __restrict__ kv, const float* __restrict__ dtsT,
    const float* __restrict__ BT, const float* __restrict__ alg,
    const float* __restrict__ dtw, const float* __restrict__ dtb,
    float* __restrict__ hend, float* __restrict__ Ssum)
{
    __shared__ float dts_s[CHUNK * R_];
    __shared__ float B_s[CHUNK * N_];
    const int tid = threadIdx.x;
    const int d = tid;
    const int blk = blockIdx.x;
    const int ch = blk & (NCH - 1);
    const int bk = blk >> 7;
    const int k = bk & 3;

    {
        const float* src = dtsT + ((size_t)bk * L_ + ch * CHUNK) * R_;
        if (tid < 64) *(float4*)&dts_s[4 * tid] = *(const float4*)(src + 4 * tid);
        const float* bsrc = BT + ((size_t)bk * L_ + ch * CHUNK) * N_;
        *(float4*)&B_s[4 * tid] = *(const float4*)(bsrc + 4 * tid);
    }
    float uu[CHUNK];
    {
        const float4* up = (const float4*)(kv + ((size_t)bk * D_ + d) * L_ + ch * CHUNK);
        #pragma unroll
        for (int j = 0; j < 8; ++j) {
            const float4 v = up[j];
            uu[4*j] = v.x; uu[4*j+1] = v.y; uu[4*j+2] = v.z; uu[4*j+3] = v.w;
        }
    }
    float dtwr[R_];
    {
        const float* p = dtw + ((size_t)k * D_ + d) * R_;
        *(float4*)&dtwr[0] = *(const float4*)p;
        *(float4*)&dtwr[4] = *(const float4*)(p + 4);
    }
    const float bias = dtb[k * D_ + d];
    float A2[N_];
    {
        const float* ap = alg + ((size_t)k * D_ + d) * N_;
        #pragma unroll
        for (int j = 0; j < 4; ++j) {
            float4 a = *(const float4*)(ap + 4 * j);
            A2[4*j]   = -__expf(a.x) * LOG2E; A2[4*j+1] = -__expf(a.y) * LOG2E;
            A2[4*j+2] = -__expf(a.z) * LOG2E; A2[4*j+3] = -__expf(a.w) * LOG2E;
        }
    }
    __syncthreads();

    float h[N_];
    #pragma unroll
    for (int n = 0; n < N_; ++n) h[n] = 0.f;
    float sd = 0.f;
    #pragma unroll
    for (int l = 0; l < CHUNK; ++l) {
        float dv[R_];
        *(float4*)&dv[0] = *(const float4*)&dts_s[l * R_];
        *(float4*)&dv[4] = *(const float4*)&dts_s[l * R_ + 4];
        float s = bias;
        #pragma unroll
        for (int r = 0; r < R_; ++r) s = fmaf(dv[r], dtwr[r], s);
        const float e = FEXP2(s * LOG2E);
        const float dlt = (s > 15.f) ? s : __logf(1.f + e);
        sd += dlt;
        const float xb = dlt * uu[l];
        #pragma unroll
        for (int g = 0; g < 4; ++g) {
            const float4 bg = *(const float4*)&B_s[l * N_ + 4 * g];
            h[4*g+0] = fmaf(FEXP2(dlt * A2[4*g+0]), h[4*g+0], xb * bg.x);
            h[4*g+1] = fmaf(FEXP2(dlt * A2[4*g+1]), h[4*g+1], xb * bg.y);
            h[4*g+2] = fmaf(FEXP2(dlt * A2[4*g+2]), h[4*g+2], xb * bg.z);
            h[4*g+3] = fmaf(FEXP2(dlt * A2[4*g+3]), h[4*g+3], xb * bg.w);
        }
    }
    float* hp = hend + (((size_t)bk * NCH + ch) * D_ + d) * N_;
    #pragma unroll
    for (int j = 0; j < 4; ++j) {
        float4 o; o.x = h[4*j]; o.y = h[4*j+1]; o.z = h[4*j+2]; o.w = h[4*j+3];
        *(float4*)(hp + 4 * j) = o;
    }
    Ssum[((size_t)bk * NCH + ch) * D_ + d] = sd;
}

__global__ __launch_bounds__(64, 2) void k25_chain(
    const float* __restrict__ alg, const float* __restrict__ Ssum,
    const float* __restrict__ hend, float* __restrict__ hinit)
{
    const int tg = blockIdx.x * 64 + threadIdx.x;
    const int n = tg & 15;
    const int d = (tg >> 4) & 127;
    const int bk = tg >> 11;
    const int k = bk & 3;
    const float A2 = -__expf(alg[((size_t)k * D_ + d) * N_ + n]) * LOG2E;
    float h = 0.f;
    for (int c0 = 0; c0 < NCH; c0 += 32) {
        float he[32], ss[32];
        #pragma unroll
        for (int j = 0; j < 32; ++j) {
            const size_t si = ((size_t)bk * NCH + c0 + j) * D_ + d;
            he[j] = hend[si * N_ + n];
            ss[j] = Ssum[si];
        }
        #pragma unroll
        for (int j = 0; j < 32; ++j) {
            const size_t si = ((size_t)bk * NCH + c0 + j) * D_ + d;
            hinit[si * N_ + n] = h;
            h = fmaf(FEXP2(ss[j] * A2), h, he[j]);
        }
    }
}

__global__ __launch_bounds__(128, 1) void k3_pass2(
    const float* __restrict__ kv, const float* __restrict__ dtsT,
    const float* __restrict__ BT, const float* __restrict__ CT,
    const float* __restrict__ alg, const float* __restrict__ dtw,
    const float* __restrict__ dtb, const float* __restrict__ DsG,
    const float* __restrict__ hinit, float* __restrict__ out)
{
    constexpr int YS = CHUNK + 1;
    __shared__ float dts_s[CHUNK * R_];
    __shared__ float B_s[CHUNK * N_];
    __shared__ float C_s[CHUNK * N_];
    __shared__ float y_s[D_ * YS];
    const int tid = threadIdx.x;
    const int d = tid;
    const int blk = blockIdx.x;
    const int ch = blk & (NCH - 1);
    const int bk = blk >> 7;
    const int k = bk & 3;

    {
        const float* src = dtsT + ((size_t)bk * L_ + ch * CHUNK) * R_;
        if (tid < 64) *(float4*)&dts_s[4 * tid] = *(const float4*)(src + 4 * tid);
        const float* bsrc = BT + ((size_t)bk * L_ + ch * CHUNK) * N_;
        *(float4*)&B_s[4 * tid] = *(const float4*)(bsrc + 4 * tid);
        const float* csrc = CT + ((size_t)bk * L_ + ch * CHUNK) * N_;
        *(float4*)&C_s[4 * tid] = *(const float4*)(csrc + 4 * tid);
    }
    float uu[CHUNK];
    {
        const float4* up = (const float4*)(kv + ((size_t)bk * D_ + d) * L_ + ch * CHUNK);
        #pragma unroll
        for (int j = 0; j < 8; ++j) {
            const float4 v = up[j];
            uu[4*j] = v.x; uu[4*j+1] = v.y; uu[4*j+2] = v.z; uu[4*j+3] = v.w;
        }
    }
    float dtwr[R_];
    {
        const float* p = dtw + ((size_t)k * D_ + d) * R_;
        *(float4*)&dtwr[0] = *(const float4*)p;
        *(float4*)&dtwr[4] = *(const float4*)(p + 4);
    }
    const float bias = dtb[k * D_ + d];
    const float Dv = DsG[k * D_ + d];
    float A2[N_];
    {
        const float* ap = alg + ((size_t)k * D_ + d) * N_;
        #pragma unroll
        for (int j = 0; j < 4; ++j) {
            float4 a = *(const float4*)(ap + 4 * j);
            A2[4*j]   = -__expf(a.x) * LOG2E; A2[4*j+1] = -__expf(a.y) * LOG2E;
            A2[4*j+2] = -__expf(a.z) * LOG2E; A2[4*j+3] = -__expf(a.w) * LOG2E;
        }
    }
    float h[N_];
    {
        const float* hp = hinit + (((size_t)bk * NCH + ch) * D_ + d) * N_;
        #pragma unroll
        for (int j = 0; j < 4; ++j) {
            float4 v = *(const float4*)(hp + 4 * j);
            h[4*j] = v.x; h[4*j+1] = v.y; h[4*j+2] = v.z; h[4*j+3] = v.w;
        }
    }
    __syncthreads();

    #pragma unroll
    for (int l = 0; l < CHUNK; ++l) {
        float dv[R_];
        *(float4*)&dv[0] = *(const float4*)&dts_s[l * R_];
        *(float4*)&dv[4] = *(const float4*)&dts_s[l * R_ + 4];
        float s = bias;
        #pragma unroll
        for (int r = 0; r < R_; ++r) s = fmaf(dv[r], dtwr[r], s);
        const float e = FEXP2(s * LOG2E);
        const float dlt = (s > 15.f) ? s : __logf(1.f + e);
        const float xb = dlt * uu[l];
        float p0 = 0.f, p1 = 0.f;
        #pragma unroll
        for (int g = 0; g < 4; ++g) {
            const float4 bg = *(const float4*)&B_s[l * N_ + 4 * g];
            const float4 cg4 = *(const float4*)&C_s[l * N_ + 4 * g];
            h[4*g+0] = fmaf(FEXP2(dlt * A2[4*g+0]), h[4*g+0], xb * bg.x);
            p0 = fmaf(h[4*g+0], cg4.x, p0);
            h[4*g+1] = fmaf(FEXP2(dlt * A2[4*g+1]), h[4*g+1], xb * bg.y);
            p1 = fmaf(h[4*g+1], cg4.y, p1);
            h[4*g+2] = fmaf(FEXP2(dlt * A2[4*g+2]), h[4*g+2], xb * bg.z);
            p0 = fmaf(h[4*g+2], cg4.z, p0);
            h[4*g+3] = fmaf(FEXP2(dlt * A2[4*g+3]), h[4*g+3], xb * bg.w);
            p1 = fmaf(h[4*g+3], cg4.w, p1);
        }
        y_s[d * YS + l] = fmaf(uu[l], Dv, p0 + p1);
    }
    __syncthreads();

    #pragma unroll
    for (int p = 0; p < 8; ++p) {
        const int f = tid + p * 128;
        const int row = f >> 3, j4 = (f & 7) * 4;
        const float* yp = &y_s[row * YS + j4];
        float4 o; o.x = yp[0]; o.y = yp[1]; o.z = yp[2]; o.w = yp[3];
        *(float4*)(out + ((size_t)bk * D_ + row) * L_ + ch * CHUNK + j4) = o;
    }
}

extern "C" void kernel_launch(void* const* d_in, const int* in_sizes, int n_in,
                              void* d_out, int out_size, void* d_ws, size_t ws_size,
                              hipStream_t stream)
{
    const float* qx  = (const float*)d_in[0];
    const float* kv  = (const float*)d_in[1];
    const float* xw  = (const float*)d_in[2];
    const float* dtw = (const float*)d_in[3];
    const float* dtb = (const float*)d_in[4];
    const float* alg = (const float*)d_in[5];
    const float* Ds  = (const float*)d_in[6];
    float* out = (float*)d_out;

    const size_t sz_dts = (size_t)B_ * K_ * L_ * R_;        //   262,144
    const size_t sz_bc  = (size_t)B_ * K_ * L_ * N_;        //   524,288
    const size_t sz_h   = (size_t)B_ * K_ * NCH * D_ * N_;  // 2,097,152
    const size_t sz_ss  = (size_t)B_ * K_ * NCH * D_;       //   131,072
    const size_t need = (sz_dts + 2 * sz_bc + 2 * sz_h + sz_ss) * sizeof(float);
    if (ws_size < need) return;   // ~22.5 MB (covers both paths)

    float* dts   = (float*)d_ws;
    float* BTp   = dts + sz_dts;
    float* CTp   = BTp + sz_bc;
    float* hend  = CTp + sz_bc;
    float* hinit = hend + sz_h;
    float* Ssm   = hinit + sz_h;

    void* args[] = { (void*)&qx, (void*)&kv, (void*)&xw, (void*)&dtw,
                     (void*)&dtb, (void*)&alg, (void*)&Ds,
                     (void*)&hend, (void*)&hinit, (void*)&Ssm, (void*)&out };
    hipError_t err = hipLaunchCooperativeKernel(
        (void*)fused, dim3(B_ * K_ * 32), dim3(512), args, 0, stream);

    if (err != hipSuccess) {
        // fallback: round-7 four-kernel path (identical numerics)
        k1_proj<<<B_ * K_ * 32, 640, 0, stream>>>(qx, kv, xw, dts, BTp, CTp);
        k2_pass1<<<B_ * K_ * NCH, 128, 0, stream>>>(kv, dts, BTp, alg, dtw, dtb, hend, Ssm);
        k25_chain<<<256, 64, 0, stream>>>(alg, Ssm, hend, hinit);
        k3_pass2<<<B_ * K_ * NCH, 128, 0, stream>>>(kv, dts, BTp, CTp, alg, dtw, dtb, Ds, hinit, out);
    }
}

// Round 10
// 72.631 us; speedup vs baseline: 5.1282x; 3.0260x over previous
//
#include <hip/hip_runtime.h>
#include <cmath>

namespace {
constexpr int B_ = 2, K_ = 4, D_ = 128, L_ = 4096, N_ = 16, R_ = 8, C_ = 40;
constexpr int CHUNK = 32, NCH = L_ / CHUNK;   // 128 chunks of 32
constexpr float LOG2E = 1.44269504f;
}

#if __has_builtin(__builtin_amdgcn_exp2f)
#define FEXP2(x) __builtin_amdgcn_exp2f(x)
#else
#define FEXP2(x) exp2f(x)
#endif

// ===========================================================================
// kA: projections + pass-1, fused (block-local dependency only, NO grid sync).
// Grid 256 (bk,lt) x 512 thr. Phase A: 8 waves x 10 jobs -> global dts/BT/CT.
// syncthreads. Stage dts/B into LDS (L1/L2-hot). Phase B: load uu AFTER phase
// A (short live range, no spill), pass-1 scan -> hend/Ssum.
// ===========================================================================
__global__ __launch_bounds__(512) void kA_proj_pass1(
    const float* __restrict__ qx, const float* __restrict__ kv,
    const float* __restrict__ xw, const float* __restrict__ dtw,
    const float* __restrict__ dtb, const float* __restrict__ alg,
    float* __restrict__ dtsT, float* __restrict__ BT, float* __restrict__ CT,
    float* __restrict__ hend, float* __restrict__ Ssum)
{
    __shared__ float Wt[D_ * C_];        // 20.5 KB [d][c]
    __shared__ float dts_s[128 * R_];    //  4 KB   [l][r]
    __shared__ float B_s[128 * N_];      //  8 KB   [l][n]

    const int tid = threadIdx.x;
    const int w = tid >> 6, lane = tid & 63;
    const int bk = blockIdx.x >> 5;      // 0..7
    const int k  = bk & 3;
    const int lt = blockIdx.x & 31;      // l-tile of 128

    // ---- Phase A: projections (10 jobs over 8 waves) ----
    for (int i = tid; i < C_ * D_; i += 512) {
        const int c = i >> 7, dd = i & 127;
        Wt[dd * C_ + c] = xw[(k * C_ + c) * D_ + dd];
    }
    __syncthreads();
    {
        const int dg = lane >> 5, lq = lane & 31;
        for (int job = w; job < 10; job += 8) {
            const float* xsrc = (job >= 6) ? qx : kv;
            const int c0 = job * 4;
            float acc[4][4];
            #pragma unroll
            for (int c = 0; c < 4; ++c)
                #pragma unroll
                for (int j = 0; j < 4; ++j) acc[c][j] = 0.f;

            const float* src = xsrc + ((size_t)bk * D_ + dg * 64) * L_ + lt * 128 + 4 * lq;
            #pragma unroll 8
            for (int dd = 0; dd < 64; ++dd) {
                const float4 x = *(const float4*)(src + (size_t)dd * L_);
                const float4 wv = *(const float4*)&Wt[(dg * 64 + dd) * C_ + c0];
                const float* wp = (const float*)&wv;
                #pragma unroll
                for (int c = 0; c < 4; ++c) {
                    acc[c][0] = fmaf(x.x, wp[c], acc[c][0]);
                    acc[c][1] = fmaf(x.y, wp[c], acc[c][1]);
                    acc[c][2] = fmaf(x.z, wp[c], acc[c][2]);
                    acc[c][3] = fmaf(x.w, wp[c], acc[c][3]);
                }
            }
            #pragma unroll
            for (int c = 0; c < 4; ++c)
                #pragma unroll
                for (int j = 0; j < 4; ++j)
                    acc[c][j] += __shfl_xor(acc[c][j], 32, 64);

            if (dg == 0) {
                #pragma unroll
                for (int j = 0; j < 4; ++j) {
                    const int l = lt * 128 + 4 * lq + j;
                    float4 o; o.x = acc[0][j]; o.y = acc[1][j]; o.z = acc[2][j]; o.w = acc[3][j];
                    if (job < 2)
                        *(float4*)(dtsT + ((size_t)bk * L_ + l) * R_ + job * 4) = o;
                    else if (job < 6)
                        *(float4*)(BT + ((size_t)bk * L_ + l) * N_ + (job - 2) * 4) = o;
                    else
                        *(float4*)(CT + ((size_t)bk * L_ + l) * N_ + (job - 6) * 4) = o;
                }
            }
        }
    }
    __syncthreads();   // vmcnt drained: dts/BT visible block-wide via L1/L2

    // ---- Stage this l-tile's dts/B into LDS (hot reads) ----
    {
        const float4* s1 = (const float4*)(dtsT + ((size_t)bk * L_ + lt * 128) * R_);
        if (tid < 256) ((float4*)dts_s)[tid] = s1[tid];
        const float4* s2 = (const float4*)(BT + ((size_t)bk * L_ + lt * 128) * N_);
        ((float4*)B_s)[tid] = s2[tid];
    }

    // ---- Phase B setup (loads AFTER phase A: short live ranges) ----
    const int chl = tid >> 7;            // chunk-local 0..3
    const int d   = tid & 127;
    const int ch  = lt * 4 + chl;

    float uu[CHUNK];
    {
        const float4* up = (const float4*)(kv + ((size_t)bk * D_ + d) * L_ + ch * CHUNK);
        #pragma unroll
        for (int j = 0; j < 8; ++j) {
            const float4 v = up[j];
            uu[4*j] = v.x; uu[4*j+1] = v.y; uu[4*j+2] = v.z; uu[4*j+3] = v.w;
        }
    }
    float dtwr[R_];
    {
        const float* p = dtw + ((size_t)k * D_ + d) * R_;
        *(float4*)&dtwr[0] = *(const float4*)p;
        *(float4*)&dtwr[4] = *(const float4*)(p + 4);
    }
    const float bias = dtb[k * D_ + d];
    float A2[N_];
    {
        const float* ap = alg + ((size_t)k * D_ + d) * N_;
        #pragma unroll
        for (int j = 0; j < 4; ++j) {
            float4 a = *(const float4*)(ap + 4 * j);
            A2[4*j]   = -__expf(a.x) * LOG2E; A2[4*j+1] = -__expf(a.y) * LOG2E;
            A2[4*j+2] = -__expf(a.z) * LOG2E; A2[4*j+3] = -__expf(a.w) * LOG2E;
        }
    }
    __syncthreads();

    // ---- Phase B: pass-1 scan ----
    float h[N_];
    #pragma unroll
    for (int n = 0; n < N_; ++n) h[n] = 0.f;
    float sd = 0.f;

    #pragma unroll
    for (int l = 0; l < CHUNK; ++l) {
        const int ll = chl * 32 + l;
        float dv[R_];
        *(float4*)&dv[0] = *(const float4*)&dts_s[ll * R_];
        *(float4*)&dv[4] = *(const float4*)&dts_s[ll * R_ + 4];
        float s = bias;
        #pragma unroll
        for (int r = 0; r < R_; ++r) s = fmaf(dv[r], dtwr[r], s);
        const float e = FEXP2(s * LOG2E);
        const float dl = (s > 15.f) ? s : __logf(1.f + e);
        sd += dl;
        const float xb = dl * uu[l];
        #pragma unroll
        for (int g = 0; g < 4; ++g) {
            const float4 bg = *(const float4*)&B_s[ll * N_ + 4 * g];
            h[4*g+0] = fmaf(FEXP2(dl * A2[4*g+0]), h[4*g+0], xb * bg.x);
            h[4*g+1] = fmaf(FEXP2(dl * A2[4*g+1]), h[4*g+1], xb * bg.y);
            h[4*g+2] = fmaf(FEXP2(dl * A2[4*g+2]), h[4*g+2], xb * bg.z);
            h[4*g+3] = fmaf(FEXP2(dl * A2[4*g+3]), h[4*g+3], xb * bg.w);
        }
    }
    float* hp = hend + (((size_t)bk * NCH + ch) * D_ + d) * N_;
    #pragma unroll
    for (int j = 0; j < 4; ++j) {
        float4 o; o.x = h[4*j]; o.y = h[4*j+1]; o.z = h[4*j+2]; o.w = h[4*j+3];
        *(float4*)(hp + 4 * j) = o;
    }
    Ssum[((size_t)bk * NCH + ch) * D_ + d] = sd;
}

// ---------------------------------------------------------------------------
// k25: serial chunk chain, hend -> hinit (exclusive prefix), batched loads.
// ---------------------------------------------------------------------------
__global__ __launch_bounds__(64, 2) void k25_chain(
    const float* __restrict__ alg, const float* __restrict__ Ssum,
    const float* __restrict__ hend, float* __restrict__ hinit)
{
    const int tg = blockIdx.x * 64 + threadIdx.x;   // 16384 threads
    const int n = tg & 15;
    const int d = (tg >> 4) & 127;
    const int bk = tg >> 11;
    const int k = bk & 3;

    const float A2 = -__expf(alg[((size_t)k * D_ + d) * N_ + n]) * LOG2E;
    float h = 0.f;
    for (int c0 = 0; c0 < NCH; c0 += 32) {
        float he[32], ss[32];
        #pragma unroll
        for (int j = 0; j < 32; ++j) {
            const size_t si = ((size_t)bk * NCH + c0 + j) * D_ + d;
            he[j] = hend[si * N_ + n];
            ss[j] = Ssum[si];
        }
        #pragma unroll
        for (int j = 0; j < 32; ++j) {
            const size_t si = ((size_t)bk * NCH + c0 + j) * D_ + d;
            hinit[si * N_ + n] = h;
            h = fmaf(FEXP2(ss[j] * A2), h, he[j]);
        }
    }
}

// ---------------------------------------------------------------------------
// k3: pass-2 (r7 verbatim). u direct from kv; y(+u*Ds) via stride-33 LDS
// transpose tile, flushed coalesced d-major.
// ---------------------------------------------------------------------------
__global__ __launch_bounds__(128, 1) void k3_pass2(
    const float* __restrict__ kv, const float* __restrict__ dtsT,
    const float* __restrict__ BT, const float* __restrict__ CT,
    const float* __restrict__ alg, const float* __restrict__ dtw,
    const float* __restrict__ dtb, const float* __restrict__ DsG,
    const float* __restrict__ hinit, float* __restrict__ out)
{
    constexpr int YS = CHUNK + 1;
    __shared__ float dts_s[CHUNK * R_];
    __shared__ float B_s[CHUNK * N_];
    __shared__ float C_s[CHUNK * N_];
    __shared__ float y_s[D_ * YS];
    const int tid = threadIdx.x;
    const int d = tid;
    const int blk = blockIdx.x;
    const int ch = blk & (NCH - 1);
    const int bk = blk >> 7;
    const int k = bk & 3;

    {
        const float* src = dtsT + ((size_t)bk * L_ + ch * CHUNK) * R_;
        if (tid < 64) *(float4*)&dts_s[4 * tid] = *(const float4*)(src + 4 * tid);
        const float* bsrc = BT + ((size_t)bk * L_ + ch * CHUNK) * N_;
        *(float4*)&B_s[4 * tid] = *(const float4*)(bsrc + 4 * tid);
        const float* csrc = CT + ((size_t)bk * L_ + ch * CHUNK) * N_;
        *(float4*)&C_s[4 * tid] = *(const float4*)(csrc + 4 * tid);
    }
    float uu[CHUNK];
    {
        const float4* up = (const float4*)(kv + ((size_t)bk * D_ + d) * L_ + ch * CHUNK);
        #pragma unroll
        for (int j = 0; j < 8; ++j) {
            const float4 v = up[j];
            uu[4*j] = v.x; uu[4*j+1] = v.y; uu[4*j+2] = v.z; uu[4*j+3] = v.w;
        }
    }
    float dtwr[R_];
    {
        const float* p = dtw + ((size_t)k * D_ + d) * R_;
        *(float4*)&dtwr[0] = *(const float4*)p;
        *(float4*)&dtwr[4] = *(const float4*)(p + 4);
    }
    const float bias = dtb[k * D_ + d];
    const float Dv = DsG[k * D_ + d];
    float A2[N_];
    {
        const float* ap = alg + ((size_t)k * D_ + d) * N_;
        #pragma unroll
        for (int j = 0; j < 4; ++j) {
            float4 a = *(const float4*)(ap + 4 * j);
            A2[4*j]   = -__expf(a.x) * LOG2E; A2[4*j+1] = -__expf(a.y) * LOG2E;
            A2[4*j+2] = -__expf(a.z) * LOG2E; A2[4*j+3] = -__expf(a.w) * LOG2E;
        }
    }
    float h[N_];
    {
        const float* hp = hinit + (((size_t)bk * NCH + ch) * D_ + d) * N_;
        #pragma unroll
        for (int j = 0; j < 4; ++j) {
            float4 v = *(const float4*)(hp + 4 * j);
            h[4*j] = v.x; h[4*j+1] = v.y; h[4*j+2] = v.z; h[4*j+3] = v.w;
        }
    }
    __syncthreads();

    #pragma unroll
    for (int l = 0; l < CHUNK; ++l) {
        float dv[R_];
        *(float4*)&dv[0] = *(const float4*)&dts_s[l * R_];
        *(float4*)&dv[4] = *(const float4*)&dts_s[l * R_ + 4];
        float s = bias;
        #pragma unroll
        for (int r = 0; r < R_; ++r) s = fmaf(dv[r], dtwr[r], s);
        const float e = FEXP2(s * LOG2E);
        const float dlt = (s > 15.f) ? s : __logf(1.f + e);
        const float xb = dlt * uu[l];
        float p0 = 0.f, p1 = 0.f;
        #pragma unroll
        for (int g = 0; g < 4; ++g) {
            const float4 bg = *(const float4*)&B_s[l * N_ + 4 * g];
            const float4 cg4 = *(const float4*)&C_s[l * N_ + 4 * g];
            h[4*g+0] = fmaf(FEXP2(dlt * A2[4*g+0]), h[4*g+0], xb * bg.x);
            p0 = fmaf(h[4*g+0], cg4.x, p0);
            h[4*g+1] = fmaf(FEXP2(dlt * A2[4*g+1]), h[4*g+1], xb * bg.y);
            p1 = fmaf(h[4*g+1], cg4.y, p1);
            h[4*g+2] = fmaf(FEXP2(dlt * A2[4*g+2]), h[4*g+2], xb * bg.z);
            p0 = fmaf(h[4*g+2], cg4.z, p0);
            h[4*g+3] = fmaf(FEXP2(dlt * A2[4*g+3]), h[4*g+3], xb * bg.w);
            p1 = fmaf(h[4*g+3], cg4.w, p1);
        }
        y_s[d * YS + l] = fmaf(uu[l], Dv, p0 + p1);
    }
    __syncthreads();

    #pragma unroll
    for (int p = 0; p < 8; ++p) {
        const int f = tid + p * 128;
        const int row = f >> 3, j4 = (f & 7) * 4;
        const float* yp = &y_s[row * YS + j4];
        float4 o; o.x = yp[0]; o.y = yp[1]; o.z = yp[2]; o.w = yp[3];
        *(float4*)(out + ((size_t)bk * D_ + row) * L_ + ch * CHUNK + j4) = o;
    }
}

extern "C" void kernel_launch(void* const* d_in, const int* in_sizes, int n_in,
                              void* d_out, int out_size, void* d_ws, size_t ws_size,
                              hipStream_t stream)
{
    const float* qx  = (const float*)d_in[0];
    const float* kv  = (const float*)d_in[1];
    const float* xw  = (const float*)d_in[2];
    const float* dtw = (const float*)d_in[3];
    const float* dtb = (const float*)d_in[4];
    const float* alg = (const float*)d_in[5];
    const float* Ds  = (const float*)d_in[6];
    float* out = (float*)d_out;

    const size_t sz_dts = (size_t)B_ * K_ * L_ * R_;        //   262,144
    const size_t sz_bc  = (size_t)B_ * K_ * L_ * N_;        //   524,288
    const size_t sz_h   = (size_t)B_ * K_ * NCH * D_ * N_;  // 2,097,152
    const size_t sz_ss  = (size_t)B_ * K_ * NCH * D_;       //   131,072
    const size_t need = (sz_dts + 2 * sz_bc + 2 * sz_h + sz_ss) * sizeof(float);
    if (ws_size < need) return;   // ~22.5 MB

    float* dts   = (float*)d_ws;
    float* BTp   = dts + sz_dts;
    float* CTp   = BTp + sz_bc;
    float* hend  = CTp + sz_bc;
    float* hinit = hend + sz_h;
    float* Ssm   = hinit + sz_h;

    kA_proj_pass1<<<B_ * K_ * 32, 512, 0, stream>>>(qx, kv, xw, dtw, dtb, alg,
                                                    dts, BTp, CTp, hend, Ssm);
    k25_chain<<<256, 64, 0, stream>>>(alg, Ssm, hend, hinit);
    k3_pass2<<<B_ * K_ * NCH, 128, 0, stream>>>(kv, dts, BTp, CTp, alg, dtw, dtb, Ds, hinit, out);
}